// Round 3
// baseline (188.183 us; speedup 1.0000x reference)
//
#include <hip/hip_runtime.h>
#include <hip/hip_cooperative_groups.h>
#include <math.h>

namespace cg = cooperative_groups;

typedef unsigned short u16;
typedef unsigned int   u32;
typedef unsigned long long u64;
typedef __attribute__((ext_vector_type(4))) unsigned short u16x4;
typedef __attribute__((ext_vector_type(8))) unsigned short bf16x8;
typedef __attribute__((ext_vector_type(8))) short sh8;      // MFMA A/B frag (8 bf16)
typedef __attribute__((ext_vector_type(4))) float f32x4;    // MFMA C/D frag

#define BT     4096
#define D      2048
#define NC     8
#define NCOL   144     // 64 selW + 64 upd + 8 mu + 8 zero-pad (9 MFMA col-tiles)
#define NSL    8       // K-slices (LDS slabs); wave pair (ctg 0/1) shares a slice
#define KR     (D / NSL)  // 256 per K-slice
#define TPB    16      // tokens per block
#define LPAD   (NCOL + 4) // LDS row pad (stride 148: kills pow2 bank pattern)

__device__ __forceinline__ float bf2f(u16 v) {
    u32 u = ((u32)v) << 16;
    float f; __builtin_memcpy(&f, &u, 4); return f;
}
__device__ __forceinline__ u16 f2bf(float f) {
    u32 u; __builtin_memcpy(&u, &f, 4);
    u += 0x7fffu + ((u >> 16) & 1);        // RNE
    return (u16)(u >> 16);
}

// ---------------------------------------------------------------------------
// Inline dtype detector (validated by A/B in prior session): fp32 bit
// patterns read as bf16 give |v|>1e4 or NaN w.p.~1; genuine bf16 N(0,1) stays
// |v|<6. All waves check the SAME 256 elements -> block-uniform flag.
// ---------------------------------------------------------------------------
__device__ __forceinline__ int detect_fp32(const void* xv) {
    const u16* p = (const u16*)xv;
    int l = threadIdx.x & 63;
    bool bad = false;
#pragma unroll
    for (int i = 0; i < 4; i++) {
        float v = bf2f(p[l * 4 + i]);
        if (!(fabsf(v) < 1e4f)) bad = true;   // catches NaN too
    }
    return __ballot(bad) != 0ull;
}

// ---- dtype-polymorphic loads: DT=0 bf16 buffers, DT=1 fp32 buffers ----
template<int DT> struct IO;
template<> struct IO<0> {
    static __device__ __forceinline__ float ld1(const void* p, size_t i) {
        return bf2f(((const u16*)p)[i]);
    }
    static __device__ __forceinline__ void ld4(const void* p, size_t i, float* o) {
        u16x4 v = *(const u16x4*)((const u16*)p + i);
#pragma unroll
        for (int k = 0; k < 4; k++) o[k] = bf2f(v[k]);
    }
    static __device__ __forceinline__ void ld8(const void* p, size_t i, float* o) {
        bf16x8 v = *(const bf16x8*)((const u16*)p + i);
#pragma unroll
        for (int k = 0; k < 8; k++) o[k] = bf2f(v[k]);
    }
    static __device__ __forceinline__ void st4(void* p, size_t i, const float* v) {
        u16x4 o;
#pragma unroll
        for (int k = 0; k < 4; k++) o[k] = f2bf(v[k]);
        *(u16x4*)((u16*)p + i) = o;
    }
    static __device__ __forceinline__ u16 ldbf(const void* p, size_t i) {
        return ((const u16*)p)[i];
    }
    static __device__ __forceinline__ sh8 afrag(const void* p, size_t i) {
        return *(const sh8*)((const u16*)p + i);
    }
};
template<> struct IO<1> {
    static __device__ __forceinline__ float ld1(const void* p, size_t i) {
        return ((const float*)p)[i];
    }
    static __device__ __forceinline__ void ld4(const void* p, size_t i, float* o) {
        f32x4 a = *(const f32x4*)((const float*)p + i);
#pragma unroll
        for (int k = 0; k < 4; k++) o[k] = a[k];
    }
    static __device__ __forceinline__ void ld8(const void* p, size_t i, float* o) {
        f32x4 a = *(const f32x4*)((const float*)p + i);
        f32x4 b = *(const f32x4*)((const float*)p + i + 4);
#pragma unroll
        for (int k = 0; k < 4; k++) { o[k] = a[k]; o[4 + k] = b[k]; }
    }
    static __device__ __forceinline__ void st4(void* p, size_t i, const float* v) {
        f32x4 a;
#pragma unroll
        for (int k = 0; k < 4; k++) a[k] = v[k];
        *(f32x4*)((float*)p + i) = a;
    }
    static __device__ __forceinline__ u16 ldbf(const void* p, size_t i) {
        return f2bf(((const float*)p)[i]);
    }
    static __device__ __forceinline__ sh8 afrag(const void* p, size_t i) {
        f32x4 a = *(const f32x4*)((const float*)p + i);
        f32x4 b = *(const f32x4*)((const float*)p + i + 4);
        sh8 r;
#pragma unroll
        for (int k = 0; k < 4; k++) {
            r[k]     = (short)f2bf(a[k]);
            r[4 + k] = (short)f2bf(b[k]);
        }
        return r;
    }
};

// ---------------------------------------------------------------------------
// Phase 0 (prep), flat-mapped over blocks 0..67 (others idle to grid.sync):
//  blocks  0..35: WtT bf16 [144][2048] (B^T): rows 0..63 selW[n][:,s],
//                 64..127 upd[n][:,h], 128..135 mu[n], 136..143 zeros
//  blocks 36..51: per-concept const PARTIALS, 4 groups of 256 thr per block;
//                 plain-stored gPart[pid][17], summed post-sync.
//  blocks 52..67: DGN -> bf16 repack
// ---------------------------------------------------------------------------
template<int DT>
__device__ __forceinline__ void prep_phase(const void* selW, const void* upd,
                                           const void* mu, const void* deb,
                                           const void* dgn,
                                           u16* __restrict__ WtT,
                                           float* __restrict__ gPart,
                                           u16* __restrict__ dgnb,
                                           float (*red)[17]) {
    const int b = blockIdx.x, t = threadIdx.x;
    if (b < 36) {
        int j = b * 4 + (t >> 8), d0 = (t & 255) * 8;
        bf16x8 v;
        if (j < 64) {
            int n = j >> 3, s = j & 7;
#pragma unroll
            for (int i = 0; i < 8; i++) v[i] = IO<DT>::ldbf(selW, ((size_t)n * D + d0 + i) * 8 + s);
        } else if (j < 128) {
            int n = (j - 64) >> 3, h = j & 7;
#pragma unroll
            for (int i = 0; i < 8; i++) v[i] = IO<DT>::ldbf(upd, ((size_t)n * D + d0 + i) * 8 + h);
        } else if (j < 136) {
#pragma unroll
            for (int i = 0; i < 8; i++) v[i] = IO<DT>::ldbf(mu, (size_t)(j - 128) * D + d0 + i);
        } else {
#pragma unroll
            for (int i = 0; i < 8; i++) v[i] = 0;
        }
        *(bf16x8*)(WtT + (size_t)j * D + d0) = v;
    } else if (b < 52) {
        int pid = (b - 36) * 4 + (t >> 8);   // 0..63 = (n<<3)|chunk
        int n = pid >> 3;
        int d = (pid & 7) * 256 + (t & 255);

        float mud = IO<DT>::ld1(mu,  (size_t)n * D + d);
        float dbd = IO<DT>::ld1(deb, (size_t)n * D + d);
        float m2 = mud * mud;
        float wv[8], uv[8], o[8], u[8];
        IO<DT>::ld8(selW, ((size_t)n * D + d) * 8, wv);
        IO<DT>::ld8(upd,  ((size_t)n * D + d) * 8, uv);
#pragma unroll
        for (int s = 0; s < 8; s++) { o[s] = wv[s] * mud; u[s] = uv[s] * dbd; }

#pragma unroll
        for (int i = 1; i < 64; i <<= 1) {
            m2 += __shfl_xor(m2, i, 64);
#pragma unroll
            for (int s = 0; s < 8; s++) {
                o[s] += __shfl_xor(o[s], i, 64);
                u[s] += __shfl_xor(u[s], i, 64);
            }
        }
        if ((t & 63) == 0) {
            int w = t >> 6;
            red[w][0] = m2;
#pragma unroll
            for (int s = 0; s < 8; s++) { red[w][1 + s] = o[s]; red[w][9 + s] = u[s]; }
        }
        __syncthreads();
        if ((t & 255) < 17) {
            int g = t >> 8, k = t & 255;
            float acc = red[g * 4 + 0][k] + red[g * 4 + 1][k]
                      + red[g * 4 + 2][k] + red[g * 4 + 3][k];
            gPart[pid * 17 + k] = acc;     // plain store — group owns its slot
        }
    } else if (b < 68) {
        int idx = (b - 52) * 1024 + t;     // 16384 tasks x 8 elems = all of dgn
        float v[8];
        IO<DT>::ld8(dgn, (size_t)idx * 8, v);
        bf16x8 o;
#pragma unroll
        for (int k = 0; k < 8; k++) o[k] = f2bf(v[k]);
        *(bf16x8*)(dgnb + (size_t)idx * 8) = o;
    }
}

// ---------------------------------------------------------------------------
// Phase 1-3 (fused gemm+gate+blend), 16 tokens/block, 256 blocks x 1024 thr.
//  Wave w: kslice = w&7 (K range [kslice*256, +256)), ctg = w>>3 (col-tile
//  group: ctg0 -> ct 0..4, ctg1 -> ct 4..8; the shared ct=4 tile computes
//  bit-identically in both -> benign same-value LDS double-write).
//  acc shrinks 36->20 VGPRs and the per-ks B-batch 36->20, leaving room
//  (128 VGPR cap at 16 waves/CU) for an explicit next-ks prefetch.
//  Phase 2: gate over 8 slabs (128 threads), verified math/tie-break.
//  Phase 2b: 16 threads rank tokens by winning concept -> ordL.
//  Phase 3: blend in ordL order (same-concept tokens adjacent -> DGNB/BIAS
//  rows L1-hit), two 512-thread halves x 8 tokens, 4 d's/thread.
// ---------------------------------------------------------------------------
template<int DT>
__device__ __forceinline__ void fused_phase(
    const void* X, const u16* __restrict__ WtT, const float* __restrict__ gPart,
    const u16* __restrict__ DGNB, const void* BIAS,
    const void* CENTER, const void* SLOPE, void* OUT,
    float (*LP)[TPB][LPAD], float (*LS2)[TPB],
    float (*cOFF)[8], float (*cUB)[8], float* cMU2,
    float (*mxL)[8], float* svalL, int* cL, int* ordL) {

    const int t = threadIdx.x;
    const int w = t >> 6, l = t & 63;
    const int m = l & 15, q = l >> 4;
    const int tok0 = blockIdx.x * TPB;
    const int kslice = w & 7, ctg = w >> 3;
    const int k0 = kslice * KR;
    const int ctbase = ctg * 4;            // ct = ctbase + j, j = 0..4

    // consts: sum the 8 per-chunk partials per concept into LDS (t<136).
    // Ordered before gate reads by the post-gemm barrier.
    if (t < 136) {
        int n = t / 17, k = t % 17;
        float s = 0.f;
#pragma unroll
        for (int j = 0; j < 8; j++) s += gPart[(n * 8 + j) * 17 + k];
        if (k == 0)      cMU2[n] = s;
        else if (k < 9)  cOFF[n][k - 1] = s;
        else             cUB[n][k - 9] = s;
    }

    // ---- phase 1: gemm over (kslice, ct-group) with 1-deep prefetch ----
    const size_t aoff = (size_t)(tok0 + m) * D + k0 + q * 8;
    const u16* bp = WtT + (size_t)(m + ctbase * 16) * D + k0 + q * 8;

    f32x4 acc[5];
#pragma unroll
    for (int j = 0; j < 5; j++) acc[j] = (f32x4){0.f, 0.f, 0.f, 0.f};
    float s2 = 0.f;

    sh8 aC, aN, bC[5], bN[5];
    aC = IO<DT>::afrag(X, aoff);
#pragma unroll
    for (int j = 0; j < 5; j++) bC[j] = *(const sh8*)(bp + (size_t)j * 16 * D);

#pragma unroll
    for (int ks = 0; ks < KR / 32; ks++) {
        if (ks < KR / 32 - 1) {            // prefetch next k-step
            aN = IO<DT>::afrag(X, aoff + (ks + 1) * 32);
#pragma unroll
            for (int j = 0; j < 5; j++)
                bN[j] = *(const sh8*)(bp + (size_t)j * 16 * D + (ks + 1) * 32);
        }
        if (ctg == 0) {                    // wave-uniform: sum(x^2) once per k
#pragma unroll
            for (int i = 0; i < 8; i++) {
                float xv = bf2f((u16)aC[i]);
                s2 = fmaf(xv, xv, s2);
            }
        }
#pragma unroll
        for (int j = 0; j < 5; j++)
            acc[j] = __builtin_amdgcn_mfma_f32_16x16x32_bf16(aC, bC[j], acc[j], 0, 0, 0);
        aC = aN;
#pragma unroll
        for (int j = 0; j < 5; j++) bC[j] = bN[j];
    }

    // per-token partial sum(x^2) over this K slice: reduce over q (ctg0 only)
    if (ctg == 0) {
        s2 += __shfl_xor(s2, 16, 64);
        s2 += __shfl_xor(s2, 32, 64);
        if (l < 16) LS2[kslice][l] = s2;
    }

    // partial P tile -> this slice's LDS slab (2-way bank alias only: free)
#pragma unroll
    for (int j = 0; j < 5; j++)
#pragma unroll
        for (int r = 0; r < 4; r++)
            LP[kslice][q * 4 + r][(ctbase + j) * 16 + m] = acc[j][r];
    __syncthreads();

    // ---- phase 2: gate (128 threads = 16 tokens x 8 concepts) ----
    if (t < 128) {
        const int tok = t >> 3, n = t & 7;
        float sx2 = 0.f;
#pragma unroll
        for (int u = 0; u < NSL; u++) sx2 += LS2[u][tok];

        float pa[8];
#pragma unroll
        for (int s = 0; s < 8; s++) {
            float v = 0.f;
#pragma unroll
            for (int u = 0; u < NSL; u++) v += LP[u][tok][n * 8 + s];
            pa[s] = v;
        }
        float mdot = 0.f;
#pragma unroll
        for (int u = 0; u < NSL; u++) mdot += LP[u][tok][128 + n];

        float norm2 = sx2 - 2.f * mdot + cMU2[n];
        float sc = 0.f;
#pragma unroll
        for (int s = 0; s < 8; s++) {
            float dd = pa[s] - cOFF[n][s];
            sc += dd * dd;
        }
        sc /= norm2;
        float zv = IO<DT>::ld1(SLOPE, n) * (sc - IO<DT>::ld1(CENTER, n));
        int iv = n;
#pragma unroll
        for (int i = 1; i < 8; i <<= 1) {          // first-max tie-break == np.argmax
            float z2 = __shfl_xor(zv, i, 64);
            int   i2 = __shfl_xor(iv, i, 64);
            if (z2 > zv || (z2 == zv && i2 < iv)) { zv = z2; iv = i2; }
        }
        const int c = iv;
        float mxv = 0.f;
#pragma unroll
        for (int u = 0; u < NSL; u++) mxv += LP[u][tok][64 + c * 8 + n];
        mxL[tok][n] = mxv - cUB[c][n];
        if (n == 0) { svalL[tok] = 1.f / (1.f + expf(-zv)); cL[tok] = c; }
    }
    __syncthreads();

    // ---- phase 2b: rank tokens by concept (stable) -> ordL ----
    if (t < 16) {
        int c = cL[t], r = 0;
#pragma unroll
        for (int t2 = 0; t2 < 16; ++t2) {
            int c2 = cL[t2];
            if (c2 < c || (c2 == c && t2 < t)) r++;
        }
        ordL[r] = t;
    }
    __syncthreads();

    // ---- phase 3: blend, concept-grouped order (DGNB/BIAS L1 reuse) ----
    const int half = t >> 9;            // 0 or 1: ranks 0..7 / 8..15
    const int tid  = t & 511;
    const int d0   = tid * 4;
#pragma unroll 2
    for (int ti = 0; ti < TPB / 2; ++ti) {
        const int tok = ordL[half * (TPB / 2) + ti];
        const int c = cL[tok];
        const float sval = svalL[tok];
        float mxa[8];
#pragma unroll
        for (int h = 0; h < 8; h++) mxa[h] = mxL[tok][h];   // LDS broadcast

        const size_t trow = (size_t)(tok0 + tok) * D;
        float xf[4], bv[4], ov[4];
        IO<DT>::ld4(X,    trow + d0, xf);
        IO<DT>::ld4(BIAS, (size_t)c * D + d0, bv);
#pragma unroll
        for (int i = 0; i < 4; i++) {
            bf16x8 v = *(const bf16x8*)(DGNB + ((size_t)c * D + d0 + i) * 8);
            float du = bf2f(v[0]) * mxa[0] + bf2f(v[1]) * mxa[1]
                     + bf2f(v[2]) * mxa[2] + bf2f(v[3]) * mxa[3]
                     + bf2f(v[4]) * mxa[4] + bf2f(v[5]) * mxa[5]
                     + bf2f(v[6]) * mxa[6] + bf2f(v[7]) * mxa[7];
            ov[i] = (1.f - sval) * xf[i] + sval * (bv[i] + du);   // ETA = 1.0
        }
        IO<DT>::st4(OUT, trow + d0, ov);
    }
}

__global__ __launch_bounds__(1024, 4) void k_all(
    const void* x, const void* selW, const void* mu, const void* center,
    const void* slope, const void* upd, const void* dgn, const void* biasW,
    const void* debW, u16* WtT, float* gPart, u16* dgnb, void* OUT) {
    __shared__ float LP[NSL][TPB][LPAD];     // 75.8 KB: 8 partial 16x144 tiles
    __shared__ float LS2[NSL][TPB];
    __shared__ float cOFF[8][8], cUB[8][8], cMU2[8];
    __shared__ float mxL[TPB][8], svalL[TPB];
    __shared__ int   cL[TPB], ordL[TPB];

    const int f = detect_fp32(x);
    // prep's cross-wave reduce scratch aliases LP (LP unused until post-sync)
    float (*red)[17] = (float(*)[17])(&LP[0][0][0]);

    if (f) prep_phase<1>(selW, upd, mu, debW, dgn, WtT, gPart, dgnb, red);
    else   prep_phase<0>(selW, upd, mu, debW, dgn, WtT, gPart, dgnb, red);

    cg::this_grid().sync();

    if (f) fused_phase<1>(x, WtT, gPart, dgnb, biasW, center, slope, OUT,
                          LP, LS2, cOFF, cUB, cMU2, mxL, svalL, cL, ordL);
    else   fused_phase<0>(x, WtT, gPart, dgnb, biasW, center, slope, OUT,
                          LP, LS2, cOFF, cUB, cMU2, mxL, svalL, cL, ordL);
}

// ---------------------------------------------------------------------------
extern "C" void kernel_launch(void* const* d_in, const int* in_sizes, int n_in,
                              void* d_out, int out_size, void* d_ws, size_t ws_size,
                              hipStream_t stream) {
    const void* x      = d_in[0];
    const void* selW   = d_in[1];
    const void* mu     = d_in[2];
    const void* center = d_in[3];
    const void* slope  = d_in[4];
    const void* upd    = d_in[5];
    const void* dgn    = d_in[6];
    const void* biasW  = d_in[7];
    const void* debW   = d_in[8];

    // ws: WtT 576 KB + dgnb 256 KB + gPart 4.3 KB  (~840 KB total).
    char* ws = (char*)d_ws;
    u16*   WtT   = (u16*)ws;                      // 589824 B
    u16*   dgnb  = (u16*)(ws + 589824);           // 262144 B
    float* gPart = (float*)(ws + 851968);         //   4352 B

    void* args[13] = {
        (void*)&x, (void*)&selW, (void*)&mu, (void*)&center, (void*)&slope,
        (void*)&upd, (void*)&dgn, (void*)&biasW, (void*)&debW,
        (void*)&WtT, (void*)&gPart, (void*)&dgnb, (void*)&d_out
    };
    hipLaunchCooperativeKernel((const void*)k_all, dim3(BT / TPB), dim3(1024),
                               args, 0, stream);
}

// Round 4
// 118.802 us; speedup vs baseline: 1.5840x; 1.5840x over previous
//
#include <hip/hip_runtime.h>
#include <math.h>

typedef unsigned short u16;
typedef unsigned int   u32;
typedef unsigned long long u64;
typedef __attribute__((ext_vector_type(4))) unsigned short u16x4;
typedef __attribute__((ext_vector_type(8))) unsigned short bf16x8;
typedef __attribute__((ext_vector_type(8))) short sh8;      // MFMA A/B frag (8 bf16)
typedef __attribute__((ext_vector_type(4))) float f32x4;    // MFMA C/D frag

#define BT     4096
#define D      2048
#define NC     8
#define NCOL   144     // 64 selW + 64 upd + 8 mu + 8 zero-pad (9 MFMA col-tiles)
#define NW     8       // waves per fused block = in-block K-split (R1 config: best)
#define KR     (D / NW)   // 256 per wave
#define TPB    16      // tokens per fused block
#define LPAD   (NCOL + 4) // LDS row pad (stride 148: kills pow2 bank pattern)

__device__ __forceinline__ float bf2f(u16 v) {
    u32 u = ((u32)v) << 16;
    float f; __builtin_memcpy(&f, &u, 4); return f;
}
__device__ __forceinline__ u16 f2bf(float f) {
    u32 u; __builtin_memcpy(&u, &f, 4);
    u += 0x7fffu + ((u >> 16) & 1);        // RNE
    return (u16)(u >> 16);
}

// ---------------------------------------------------------------------------
// Inline dtype detector (validated by A/B in prior session): fp32 bit
// patterns read as bf16 give |v|>1e4 or NaN w.p.~1; genuine bf16 N(0,1) stays
// |v|<6. All waves check the SAME 256 elements -> block-uniform flag.
// ---------------------------------------------------------------------------
__device__ __forceinline__ int detect_fp32(const void* xv) {
    const u16* p = (const u16*)xv;
    int l = threadIdx.x & 63;
    bool bad = false;
#pragma unroll
    for (int i = 0; i < 4; i++) {
        float v = bf2f(p[l * 4 + i]);
        if (!(fabsf(v) < 1e4f)) bad = true;   // catches NaN too
    }
    return __ballot(bad) != 0ull;
}

// ---- dtype-polymorphic loads: DT=0 bf16 buffers, DT=1 fp32 buffers ----
template<int DT> struct IO;
template<> struct IO<0> {
    static __device__ __forceinline__ float ld1(const void* p, size_t i) {
        return bf2f(((const u16*)p)[i]);
    }
    static __device__ __forceinline__ void ld4(const void* p, size_t i, float* o) {
        u16x4 v = *(const u16x4*)((const u16*)p + i);
#pragma unroll
        for (int k = 0; k < 4; k++) o[k] = bf2f(v[k]);
    }
    static __device__ __forceinline__ void ld8(const void* p, size_t i, float* o) {
        bf16x8 v = *(const bf16x8*)((const u16*)p + i);
#pragma unroll
        for (int k = 0; k < 8; k++) o[k] = bf2f(v[k]);
    }
    static __device__ __forceinline__ void st4(void* p, size_t i, const float* v) {
        u16x4 o;
#pragma unroll
        for (int k = 0; k < 4; k++) o[k] = f2bf(v[k]);
        *(u16x4*)((u16*)p + i) = o;
    }
    static __device__ __forceinline__ u16 ldbf(const void* p, size_t i) {
        return ((const u16*)p)[i];
    }
    static __device__ __forceinline__ sh8 afrag(const void* p, size_t i) {
        return *(const sh8*)((const u16*)p + i);
    }
};
template<> struct IO<1> {
    static __device__ __forceinline__ float ld1(const void* p, size_t i) {
        return ((const float*)p)[i];
    }
    static __device__ __forceinline__ void ld4(const void* p, size_t i, float* o) {
        f32x4 a = *(const f32x4*)((const float*)p + i);
#pragma unroll
        for (int k = 0; k < 4; k++) o[k] = a[k];
    }
    static __device__ __forceinline__ void ld8(const void* p, size_t i, float* o) {
        f32x4 a = *(const f32x4*)((const float*)p + i);
        f32x4 b = *(const f32x4*)((const float*)p + i + 4);
#pragma unroll
        for (int k = 0; k < 4; k++) { o[k] = a[k]; o[4 + k] = b[k]; }
    }
    static __device__ __forceinline__ void st4(void* p, size_t i, const float* v) {
        f32x4 a;
#pragma unroll
        for (int k = 0; k < 4; k++) a[k] = v[k];
        *(f32x4*)((float*)p + i) = a;
    }
    static __device__ __forceinline__ u16 ldbf(const void* p, size_t i) {
        return f2bf(((const float*)p)[i]);
    }
    static __device__ __forceinline__ sh8 afrag(const void* p, size_t i) {
        f32x4 a = *(const f32x4*)((const float*)p + i);
        f32x4 b = *(const f32x4*)((const float*)p + i + 4);
        sh8 r;
#pragma unroll
        for (int k = 0; k < 4; k++) {
            r[k]     = (short)f2bf(a[k]);
            r[4 + k] = (short)f2bf(b[k]);
        }
        return r;
    }
};

// ---------------------------------------------------------------------------
// k_prep (272 blocks):
//  0..143 : WtT bf16 in FRAG-MAJOR layout (R4): frag (w,ks,ct) = the 1 KB
//           contiguous block of the MFMA B-fragment read by k_fused's wave w
//           at k-step ks, col-tile ct. Lane l's 16 B live at
//           WtT[(((w*8+ks)*9+ct)*64 + l)*8]. Logical content is unchanged:
//           rows 0..63 selW[n][:,s], 64..127 upd[n][:,h], 128..135 mu[n],
//           136..143 zeros (row j, col d0 -> ct=j>>4, m=j&15, w=d0>>8,
//           ks=(d0>>5)&7, q=(d0>>3)&3, l=q*16+m). This turns the gemm's
//           9 scattered 16-line loads per k-step into one sequential 9 KB
//           stream per k-step (72 KB/wave) -> dense full-width L2 requests.
//  144..207: per-concept const PARTIALS — plain-stored gPart[pid][17]
//  208..271: DGN -> bf16 repack (halves blend's L2 traffic)
// ---------------------------------------------------------------------------
template<int DT>
__device__ __forceinline__ void prep_part(const void* selW, const void* upd,
                                          const void* mu, u16* __restrict__ WtT) {
    int idx = blockIdx.x * 256 + threadIdx.x;
    int j = idx >> 8, d0 = (idx & 255) * 8;
    bf16x8 v;
    if (j < 64) {
        int n = j >> 3, s = j & 7;
#pragma unroll
        for (int i = 0; i < 8; i++) v[i] = IO<DT>::ldbf(selW, ((size_t)n * D + d0 + i) * 8 + s);
    } else if (j < 128) {
        int n = (j - 64) >> 3, h = j & 7;
#pragma unroll
        for (int i = 0; i < 8; i++) v[i] = IO<DT>::ldbf(upd, ((size_t)n * D + d0 + i) * 8 + h);
    } else if (j < 136) {
#pragma unroll
        for (int i = 0; i < 8; i++) v[i] = IO<DT>::ldbf(mu, (size_t)(j - 128) * D + d0 + i);
    } else {
#pragma unroll
        for (int i = 0; i < 8; i++) v[i] = 0;
    }
    // frag-major destination (pure permutation of the old [144][2048] layout)
    int ct = j >> 4, m = j & 15;
    int w  = d0 >> 8, ks = (d0 >> 5) & 7, q = (d0 >> 3) & 3;
    size_t dst = ((((size_t)(w * 8 + ks) * 9 + ct) * 64) + q * 16 + m) * 8;
    *(bf16x8*)(WtT + dst) = v;
}

template<int DT>
__device__ __forceinline__ void consts_part(const void* W, const void* mu,
                                            const void* upd, const void* deb,
                                            float* __restrict__ gPart) {
    int pid = blockIdx.x - 144;            // 0..63 = (n<<3)|chunk
    int n = pid >> 3, t = threadIdx.x;
    int d = (pid & 7) * 256 + t;

    float mud = IO<DT>::ld1(mu,  (size_t)n * D + d);
    float dbd = IO<DT>::ld1(deb, (size_t)n * D + d);
    float m2 = mud * mud;
    float wv[8], uv[8], o[8], u[8];
    IO<DT>::ld8(W,   ((size_t)n * D + d) * 8, wv);
    IO<DT>::ld8(upd, ((size_t)n * D + d) * 8, uv);
#pragma unroll
    for (int s = 0; s < 8; s++) { o[s] = wv[s] * mud; u[s] = uv[s] * dbd; }

#pragma unroll
    for (int i = 1; i < 64; i <<= 1) {
        m2 += __shfl_xor(m2, i, 64);
#pragma unroll
        for (int s = 0; s < 8; s++) {
            o[s] += __shfl_xor(o[s], i, 64);
            u[s] += __shfl_xor(u[s], i, 64);
        }
    }
    __shared__ float red[4][17];
    int wave = t >> 6, lane = t & 63;
    if (lane == 0) {
        red[wave][0] = m2;
#pragma unroll
        for (int s = 0; s < 8; s++) { red[wave][1 + s] = o[s]; red[wave][9 + s] = u[s]; }
    }
    __syncthreads();
    if (t < 17) {
        float acc = red[0][t] + red[1][t] + red[2][t] + red[3][t];
        gPart[pid * 17 + t] = acc;         // plain store — block owns its slot
    }
}

template<int DT>
__device__ __forceinline__ void dgnb_part(const void* dgn, u16* __restrict__ dgnb) {
    int idx = (blockIdx.x - 208) * 256 + threadIdx.x;   // 16384 threads x 8 elems
    float v[8];
    IO<DT>::ld8(dgn, (size_t)idx * 8, v);
    bf16x8 o;
#pragma unroll
    for (int k = 0; k < 8; k++) o[k] = f2bf(v[k]);
    *(bf16x8*)(dgnb + (size_t)idx * 8) = o;
}

__global__ __launch_bounds__(256) void k_prep(
    const void* x, const void* selW, const void* upd, const void* mu,
    const void* deb, const void* dgn, u16* WtT, float* gPart, u16* dgnb) {
    int f = detect_fp32(x);
    if (blockIdx.x < 144) {
        if (f) prep_part<1>(selW, upd, mu, WtT); else prep_part<0>(selW, upd, mu, WtT);
    } else if (blockIdx.x < 208) {
        if (f) consts_part<1>(selW, mu, upd, deb, gPart);
        else   consts_part<0>(selW, mu, upd, deb, gPart);
    } else {
        if (f) dgnb_part<1>(dgn, dgnb); else dgnb_part<0>(dgn, dgnb);
    }
}

// ---------------------------------------------------------------------------
// k_fused (256 blocks x 512 threads): gemm + gate + blend, 16 tokens/block.
//  R4 change vs R1 (the 43.4 µs best): B-frags read from the frag-major WtT
//  — per k-step the wave's 9 loads cover one sequential 9 KB region (16 B/
//  lane contiguous within each 1 KB frag), instead of 144 cache lines
//  scattered at 4 KB stride. Everything else is byte-identical to R1.
//  Phase 1 (gemm): wave w owns K-slice [w*256, +256); MFMA 16x16x32
//    (A: lane l holds X[tok0+(l&15)][k0+(l>>4)*8..+8]; C/D row=(l>>4)*4+reg,
//    col=l&15). Partial 16x144 tile -> per-wave LDS slab.
//  Phase 2 (gate): 128 threads (tok,n), verified score/argmax/tie-break.
//  Phase 3 (blend): 512 threads x 4 d's, 16-token loop, coalesced.
// ---------------------------------------------------------------------------
template<int DT>
__device__ __forceinline__ void fused_body(
    const void* X, const u16* __restrict__ WtT, const float* __restrict__ gPart,
    const u16* __restrict__ DGNB, const void* BIAS,
    const void* CENTER, const void* SLOPE, void* OUT,
    float (*LP)[TPB][LPAD], float (*LS2)[TPB],
    float (*cOFF)[8], float (*cUB)[8], float* cMU2,
    float (*mxL)[8], float* svalL, int* cL) {

    const int t = threadIdx.x;
    const int w = t >> 6, l = t & 63;
    const int m = l & 15, q = l >> 4;
    const int tok0 = blockIdx.x * TPB;
    const int k0 = w * KR;

    // consts: sum the 8 per-chunk partials per concept into LDS (t<136).
    // Ordered before gate reads by the post-gemm barrier.
    if (t < 136) {
        int n = t / 17, k = t % 17;
        float s = 0.f;
#pragma unroll
        for (int j = 0; j < 8; j++) s += gPart[(n * 8 + j) * 17 + k];
        if (k == 0)      cMU2[n] = s;
        else if (k < 9)  cOFF[n][k - 1] = s;
        else             cUB[n][k - 9] = s;
    }

    // ---- phase 1: gemm over this wave's K slice ----
    const size_t aoff = (size_t)(tok0 + m) * D + k0 + q * 8;
    // frag-major B: wave w's stream starts at frag (w*8, ct=0); lane offset l*8
    const u16* bp = WtT + (size_t)w * (8 * 9 * 512) + (size_t)l * 8;

    f32x4 acc[9];
#pragma unroll
    for (int ct = 0; ct < 9; ct++) acc[ct] = (f32x4){0.f, 0.f, 0.f, 0.f};
    float s2 = 0.f;

#pragma unroll 2
    for (int ks = 0; ks < KR / 32; ks++) {
        sh8 a = IO<DT>::afrag(X, aoff + ks * 32);
        sh8 b[9];
#pragma unroll
        for (int ct = 0; ct < 9; ct++)
            b[ct] = *(const sh8*)(bp + (size_t)(ks * 9 + ct) * 512);
#pragma unroll
        for (int i = 0; i < 8; i++) {
            float xv = bf2f((u16)a[i]);
            s2 = fmaf(xv, xv, s2);
        }
#pragma unroll
        for (int ct = 0; ct < 9; ct++)
            acc[ct] = __builtin_amdgcn_mfma_f32_16x16x32_bf16(a, b[ct], acc[ct], 0, 0, 0);
    }

    // per-token partial sum(x^2) over this K slice: reduce over q
    s2 += __shfl_xor(s2, 16, 64);
    s2 += __shfl_xor(s2, 32, 64);
    if (l < 16) LS2[w][l] = s2;

    // partial P tile -> this wave's LDS slab (2-way bank alias only: free)
#pragma unroll
    for (int ct = 0; ct < 9; ct++)
#pragma unroll
        for (int r = 0; r < 4; r++)
            LP[w][q * 4 + r][ct * 16 + m] = acc[ct][r];
    __syncthreads();

    // ---- phase 2: gate (128 threads = 16 tokens x 8 concepts) ----
    if (t < 128) {
        const int tok = t >> 3, n = t & 7;
        float sx2 = 0.f;
#pragma unroll
        for (int u = 0; u < NW; u++) sx2 += LS2[u][tok];

        float pa[8];
#pragma unroll
        for (int s = 0; s < 8; s++) {
            float v = 0.f;
#pragma unroll
            for (int u = 0; u < NW; u++) v += LP[u][tok][n * 8 + s];
            pa[s] = v;
        }
        float mdot = 0.f;
#pragma unroll
        for (int u = 0; u < NW; u++) mdot += LP[u][tok][128 + n];

        float norm2 = sx2 - 2.f * mdot + cMU2[n];
        float sc = 0.f;
#pragma unroll
        for (int s = 0; s < 8; s++) {
            float dd = pa[s] - cOFF[n][s];
            sc += dd * dd;
        }
        sc /= norm2;
        float zv = IO<DT>::ld1(SLOPE, n) * (sc - IO<DT>::ld1(CENTER, n));
        int iv = n;
#pragma unroll
        for (int i = 1; i < 8; i <<= 1) {          // first-max tie-break == np.argmax
            float z2 = __shfl_xor(zv, i, 64);
            int   i2 = __shfl_xor(iv, i, 64);
            if (z2 > zv || (z2 == zv && i2 < iv)) { zv = z2; iv = i2; }
        }
        const int c = iv;
        float mxv = 0.f;
#pragma unroll
        for (int u = 0; u < NW; u++) mxv += LP[u][tok][64 + c * 8 + n];
        mxL[tok][n] = mxv - cUB[c][n];
        if (n == 0) { svalL[tok] = 1.f / (1.f + expf(-zv)); cL[tok] = c; }
    }
    __syncthreads();

    // ---- phase 3: blend (512 threads x 4 d's, 16-token loop) ----
    const int d0 = t * 4;
    for (int tok = 0; tok < TPB; ++tok) {
        const int c = cL[tok];
        const float sval = svalL[tok];
        float mxa[8];
#pragma unroll
        for (int h = 0; h < 8; h++) mxa[h] = mxL[tok][h];   // LDS broadcast

        const size_t trow = (size_t)(tok0 + tok) * D;
        float xf[4], bv[4], ov[4];
        IO<DT>::ld4(X,    trow + d0, xf);
        IO<DT>::ld4(BIAS, (size_t)c * D + d0, bv);
#pragma unroll
        for (int i = 0; i < 4; i++) {
            bf16x8 v = *(const bf16x8*)(DGNB + ((size_t)c * D + d0 + i) * 8);
            float du = bf2f(v[0]) * mxa[0] + bf2f(v[1]) * mxa[1]
                     + bf2f(v[2]) * mxa[2] + bf2f(v[3]) * mxa[3]
                     + bf2f(v[4]) * mxa[4] + bf2f(v[5]) * mxa[5]
                     + bf2f(v[6]) * mxa[6] + bf2f(v[7]) * mxa[7];
            ov[i] = (1.f - sval) * xf[i] + sval * (bv[i] + du);   // ETA = 1.0
        }
        IO<DT>::st4(OUT, trow + d0, ov);
    }
}

__global__ __launch_bounds__(512) void k_fused(
    const void* X, const u16* WtT, const float* gPart, const u16* DGNB,
    const void* BIAS, const void* CENTER, const void* SLOPE, void* OUT) {
    __shared__ float LP[NW][TPB][LPAD];      // 75.8 KB: 8 partial 16x144 tiles
    __shared__ float LS2[NW][TPB];
    __shared__ float cOFF[8][8], cUB[8][8], cMU2[8];
    __shared__ float mxL[TPB][8], svalL[TPB];
    __shared__ int   cL[TPB];
    if (detect_fp32(X))
        fused_body<1>(X, WtT, gPart, DGNB, BIAS, CENTER, SLOPE, OUT,
                      LP, LS2, cOFF, cUB, cMU2, mxL, svalL, cL);
    else
        fused_body<0>(X, WtT, gPart, DGNB, BIAS, CENTER, SLOPE, OUT,
                      LP, LS2, cOFF, cUB, cMU2, mxL, svalL, cL);
}

// ---------------------------------------------------------------------------
extern "C" void kernel_launch(void* const* d_in, const int* in_sizes, int n_in,
                              void* d_out, int out_size, void* d_ws, size_t ws_size,
                              hipStream_t stream) {
    const void* x      = d_in[0];
    const void* selW   = d_in[1];
    const void* mu     = d_in[2];
    const void* center = d_in[3];
    const void* slope  = d_in[4];
    const void* upd    = d_in[5];
    const void* dgn    = d_in[6];
    const void* biasW  = d_in[7];
    const void* debW   = d_in[8];

    // ws: WtT 576 KB + dgnb 256 KB + gPart 4.3 KB  (~840 KB total).
    // K-reduction + gate live entirely in LDS; no memset dispatch.
    char* ws = (char*)d_ws;
    u16*   WtT   = (u16*)ws;                      // 589824 B
    u16*   dgnb  = (u16*)(ws + 589824);           // 262144 B
    float* gPart = (float*)(ws + 851968);         //   4352 B

    k_prep <<<272, 256, 0, stream>>>(x, selW, upd, mu, debW, dgn, WtT, gPart, dgnb);
    k_fused<<<BT / TPB, 512, 0, stream>>>(x, WtT, gPart, dgnb, biasW, center, slope, d_out);
}